// Round 11
// baseline (171.589 us; speedup 1.0000x reference)
//
#include <hip/hip_runtime.h>
#include <hip/hip_bf16.h>

typedef unsigned short u16;
typedef unsigned int u32;
typedef __attribute__((ext_vector_type(8))) short short8;   // 8 bf16 (4 VGPRs)
typedef __attribute__((ext_vector_type(4))) float f32x4;    // MFMA accumulator
typedef __attribute__((ext_vector_type(4))) u16 u16x4;

static constexpr int Bb = 512, Tt = 256, Cc = 768, Hh = 64;

__device__ __forceinline__ u16 f2bf(float f) {
    __hip_bfloat16 h = __float2bfloat16(f);   // RNE
    union { __hip_bfloat16 h; u16 u; } v; v.h = h;
    return v.u;
}

// ---------------------------------------------------------------------------
// Kernel 0: Wq|Wk|Wv -> per-K-chunk fragment-major image (unchanged, proven):
//   chunk kc holds 24 frags of 1 KB: f = ksub*12 + nt; lane l of frag f gives
//   n = nt*16+(l&15), k = kc*64+ksub*32+(l>>4)*8+e.
// ---------------------------------------------------------------------------
__global__ void wt_kernel(const float* __restrict__ Wq, const float* __restrict__ Wk,
                          const float* __restrict__ Wv, u16* __restrict__ Wf) {
    int idx = blockIdx.x * 256 + threadIdx.x;          // 192*768
    int n = idx / Cc, k = idx % Cc;
    const float* W = (n < 64) ? Wq : (n < 128) ? Wk : Wv;
    float val = W[k * Hh + (n & 63)];
    int nt = n >> 4, fr = n & 15;
    int kc = k >> 6, ksub = (k >> 5) & 1, fk = k & 31;
    Wf[kc * 12288 + (ksub * 12 + nt) * 512 + (fr + ((fk >> 3) << 4)) * 8 + (fk & 7)] = f2bf(val);
}

// ---------------------------------------------------------------------------
// Fused kernel: one block per batch. 512 thr = 8 waves.
// Phase 1 (QKV GEMM, K_STEP=64, 12 chunks): NO x LDS staging — each wave
//   builds its A-fragments in registers from global (lane l: 4 float4 per
//   owned tile; the wave's loads cover 16 rows x 256 B in whole 128-B lines).
//   W reg-staged into dbuf LDS (round-10 scheme).  Per-chunk barrier is
//   lgkm-only — NO vmem drain anywhere in the loop; x loads ride 2 chunks.
// Epilogue: acc -> LDS: KT [256][64], VT [64][256], QB [256][64] -> Q frags.
// Phase 2 (causal attention, per-wave, no barriers) — unchanged (passing).
// LDS (98304 B): phase1: WS dbuf [0,49152)
//                phase2: KT [0,32768) | VT [32768,65536) | QB/P [65536,98304)
// ---------------------------------------------------------------------------
__global__ __launch_bounds__(512, 2) void fused_kernel(
        const float* __restrict__ x, const u16* __restrict__ Wf,
        const int* __restrict__ pad, float* __restrict__ out) {
    __shared__ u16 smem[49152];   // 98304 B
    char* smB = (char*)smem;

    const int tid = threadIdx.x;
    const int w = tid >> 6, l = tid & 63;
    const int lrow = l & 15, lgrp = l >> 4;
    const int b = blockIdx.x;
    const int cswz = (lrow & 7) << 4;
    const int tt0 = w, tt1 = 15 - w;          // owned query-row tiles (balanced)

    // Direct A-fragment load bases: lane l covers row tt*16+lrow, k-off lgrp*8
    const float* xga = x + ((size_t)b * Tt + tt0 * 16 + lrow) * Cc + lgrp * 8;
    const float* xgb = x + ((size_t)b * Tt + tt1 * 16 + lrow) * Cc + lgrp * 8;

    float4 xrA[8], xrB[8];
    short8 af[2][2];
    short8 wr[3];
    f32x4 acc[2][12];
#pragma unroll
    for (int i = 0; i < 2; ++i)
#pragma unroll
        for (int j = 0; j < 12; ++j) acc[i][j] = (f32x4)0.f;

// 8 float4: [tile(2)][kk(2)][half(2)]  (row-lines fully covered pairwise)
#define XLOADR(kc_, R_)                                                        \
    R_[0] = *(const float4*)(xga + (kc_) * 64);                                \
    R_[1] = *(const float4*)(xga + (kc_) * 64 + 4);                            \
    R_[2] = *(const float4*)(xga + (kc_) * 64 + 32);                           \
    R_[3] = *(const float4*)(xga + (kc_) * 64 + 36);                           \
    R_[4] = *(const float4*)(xgb + (kc_) * 64);                                \
    R_[5] = *(const float4*)(xgb + (kc_) * 64 + 4);                            \
    R_[6] = *(const float4*)(xgb + (kc_) * 64 + 32);                           \
    R_[7] = *(const float4*)(xgb + (kc_) * 64 + 36);

// regs -> bf16 A-frags: af[mt][kk][e] ; e 0..3 from R[.][e], 4..7 from R[.+1]
#define AFCONV(R_)                                                             \
    _Pragma("unroll")                                                          \
    for (int mt = 0; mt < 2; ++mt)                                             \
        _Pragma("unroll")                                                      \
        for (int kk = 0; kk < 2; ++kk) {                                       \
            float4 a0 = R_[mt * 4 + kk * 2], a1 = R_[mt * 4 + kk * 2 + 1];     \
            short8 t;                                                          \
            t[0] = (short)f2bf(a0.x); t[1] = (short)f2bf(a0.y);                \
            t[2] = (short)f2bf(a0.z); t[3] = (short)f2bf(a0.w);                \
            t[4] = (short)f2bf(a1.x); t[5] = (short)f2bf(a1.y);                \
            t[6] = (short)f2bf(a1.z); t[7] = (short)f2bf(a1.w);                \
            af[mt][kk] = t;                                                    \
        }

#define WLOADR(kc_)                                                            \
    _Pragma("unroll")                                                          \
    for (int p = 0; p < 3; ++p)                                                \
        wr[p] = *(const short8*)(Wf + (size_t)(kc_) * 12288 + (p * 8 + w) * 512 + l * 8);

#define WWRITE(nb_)                                                            \
    {                                                                          \
        u16* wl_ = smem + (nb_) * 12288;                                       \
        _Pragma("unroll")                                                      \
        for (int p = 0; p < 3; ++p)                                            \
            *(short8*)(wl_ + (p * 8 + w) * 512 + l * 8) = wr[p];               \
    }

#define COMPUTE(cur_)                                                          \
    {                                                                          \
        const char* wb = smB + (cur_) * 24576;                                 \
        _Pragma("unroll")                                                      \
        for (int ksub = 0; ksub < 2; ++ksub) {                                 \
            short8 bfr[12];                                                    \
            _Pragma("unroll")                                                  \
            for (int nt = 0; nt < 12; ++nt)                                    \
                bfr[nt] = *(const short8*)(wb + (ksub * 12 + nt) * 1024 + l * 16); \
            _Pragma("unroll")                                                  \
            for (int mt = 0; mt < 2; ++mt)                                     \
                _Pragma("unroll")                                              \
                for (int nt = 0; nt < 12; ++nt)                                \
                    acc[mt][nt] = __builtin_amdgcn_mfma_f32_16x16x32_bf16(     \
                        af[mt][ksub], bfr[nt], acc[mt][nt], 0, 0, 0);          \
        }                                                                      \
    }

// lgkm-only barrier: LDS writes visible; vmem (x prefetch) rides through.
#define LBAR() asm volatile("s_waitcnt lgkmcnt(0)\n\ts_barrier" ::: "memory")

    // ---- Phase 1 prologue ----
    XLOADR(0, xrA);
    WLOADR(0);
    XLOADR(1, xrB);
    WWRITE(0);                  // waits wr only (per-reg)
    LBAR();

    // ---- Main loop: chunks 0..9, unrolled x2 for static reg sets ----
#pragma unroll 1
    for (int ii = 0; ii < 5; ++ii) {
        const int ke = ii * 2;
        {   // chunk ke (cur=0, set A)
            WLOADR(ke + 1);
            AFCONV(xrA);        // waits xrA (loaded 2 chunks ago)
            XLOADR(ke + 2, xrA);
            COMPUTE(0);
            WWRITE(1);
            LBAR();
        }
        {   // chunk ke+1 (cur=1, set B)
            WLOADR(ke + 2);
            AFCONV(xrB);
            XLOADR(ke + 3, xrB);
            COMPUTE(1);
            WWRITE(0);
            LBAR();
        }
    }

    // ---- Chunk 10 (cur=0) ----
    WLOADR(11);
    AFCONV(xrA);
    COMPUTE(0);
    WWRITE(1);
    LBAR();
    // ---- Chunk 11 (cur=1) ----
    AFCONV(xrB);
    COMPUTE(1);
    __syncthreads();            // full fence before LDS re-purpose
#undef XLOADR
#undef AFCONV
#undef WLOADR
#undef WWRITE
#undef COMPUTE
#undef LBAR

    // ---- Epilogue: acc -> KT / VT / QB ----
#pragma unroll
    for (int mrep = 0; mrep < 2; ++mrep) {
        const int tt = (mrep == 0) ? tt0 : tt1;
        const int s0 = tt * 16;
#pragma unroll
        for (int nt = 0; nt < 12; ++nt) {
            f32x4 a = acc[mrep][nt];
            if (nt < 4) {                       // Q -> QB [256][64]
                int h = nt * 16 + lrow;
#pragma unroll
                for (int r = 0; r < 4; ++r) {
                    int row = s0 + lgrp * 4 + r;
                    *(u16*)(smB + 65536 + ((row * 128 + h * 2) ^ ((row & 7) << 4))) = f2bf(a[r]);
                }
            } else if (nt < 8) {                // K -> KT [256][64]
                int h = (nt - 4) * 16 + lrow;
#pragma unroll
                for (int r = 0; r < 4; ++r) {
                    int s = s0 + lgrp * 4 + r;
                    *(u16*)(smB + ((s * 128 + h * 2) ^ ((s & 7) << 4))) = f2bf(a[r]);
                }
            } else {                            // V -> VT [64][256]
                int h = (nt - 8) * 16 + lrow;
                int s = s0 + lgrp * 4;
                u16x4 pk;
                pk[0] = f2bf(a[0]); pk[1] = f2bf(a[1]);
                pk[2] = f2bf(a[2]); pk[3] = f2bf(a[3]);
                *(u16x4*)(smB + 32768 + h * 512 + ((s * 2) ^ ((h & 15) << 4))) = pk;
            }
        }
    }
    __syncthreads();

    // Q fragment readback
    short8 qfr[2][2];
#pragma unroll
    for (int mt = 0; mt < 2; ++mt) {
        const int tt = (mt == 0) ? tt0 : tt1;
#pragma unroll
        for (int kk = 0; kk < 2; ++kk)
            qfr[mt][kk] = *(const short8*)(smB + 65536 +
                (((tt * 16 + lrow) * 128 + kk * 64 + lgrp * 16) ^ cswz));
    }
    __syncthreads();    // all qfr reads done before P overwrites QB space

    // ---- Phase 2: causal attention (per-wave, no barriers) ----
    char* pbase = smB + 65536 + w * 2560;      // P aliases QB region
#pragma unroll
    for (int mt = 0; mt < 2; ++mt) {
        const int tt = (mt == 0) ? tt0 : tt1;
        const int i0 = tt * 16;

        f32x4 sreg[16];
#pragma unroll
        for (int t = 0; t < 16; ++t) {
            if (t <= tt) {
                short8 k0 = *(const short8*)(smB +
                    (((t * 16 + lrow) * 128 + lgrp * 16) ^ cswz));
                short8 k1 = *(const short8*)(smB +
                    (((t * 16 + lrow) * 128 + 64 + lgrp * 16) ^ cswz));
                f32x4 s = (f32x4)0.f;
                s = __builtin_amdgcn_mfma_f32_16x16x32_bf16(qfr[mt][0], k0, s, 0, 0, 0);
                s = __builtin_amdgcn_mfma_f32_16x16x32_bf16(qfr[mt][1], k1, s, 0, 0, 0);
                if (t == tt) {
#pragma unroll
                    for (int r = 0; r < 4; ++r) {
                        int i = i0 + lgrp * 4 + r;
                        int sidx = t * 16 + lrow;
                        sreg[t][r] = (sidx <= i) ? s[r] * 0.125f : -1e30f;
                    }
                } else {
#pragma unroll
                    for (int r = 0; r < 4; ++r) sreg[t][r] = s[r] * 0.125f;
                }
            }
        }

        f32x4 mx = (f32x4)(-1e30f);
#pragma unroll
        for (int t = 0; t < 16; ++t)
            if (t <= tt)
#pragma unroll
                for (int r = 0; r < 4; ++r) mx[r] = fmaxf(mx[r], sreg[t][r]);
#pragma unroll
        for (int m = 1; m <= 8; m <<= 1)
#pragma unroll
            for (int r = 0; r < 4; ++r) mx[r] = fmaxf(mx[r], __shfl_xor(mx[r], m, 64));

        f32x4 sm = (f32x4)0.f;
#pragma unroll
        for (int t = 0; t < 16; ++t)
            if (t <= tt)
#pragma unroll
                for (int r = 0; r < 4; ++r) {
                    float p = __expf(sreg[t][r] - mx[r]);
                    sreg[t][r] = p;
                    sm[r] += p;
                }
#pragma unroll
        for (int m = 1; m <= 8; m <<= 1)
#pragma unroll
            for (int r = 0; r < 4; ++r) sm[r] += __shfl_xor(sm[r], m, 64);

        float inv[4];
#pragma unroll
        for (int r = 0; r < 4; ++r) {
            int i = i0 + lgrp * 4 + r;
            inv[r] = (pad[b * Tt + i] != 0) ? (1.0f / sm[r]) : 0.0f;
        }

        f32x4 o[4];
#pragma unroll
        for (int ht = 0; ht < 4; ++ht) o[ht] = (f32x4)0.f;
#pragma unroll
        for (int ks = 0; ks < 8; ++ks) {
            if (2 * ks <= tt) {
                char* pb = pbase + (ks & 1) * 1280;
#pragma unroll
                for (int r = 0; r < 4; ++r) {
                    int prow = lgrp * 4 + r;
                    *(u16*)(pb + prow * 80 + lrow * 2) = f2bf(sreg[2 * ks][r]);
                    u16 pv2 = (2 * ks + 1 <= tt) ? f2bf(sreg[2 * ks + 1][r]) : (u16)0;
                    *(u16*)(pb + prow * 80 + 32 + lrow * 2) = pv2;
                }
                short8 pa = *(const short8*)(pb + lrow * 80 + lgrp * 16);
#pragma unroll
                for (int ht = 0; ht < 4; ++ht) {
                    short8 vfr = *(const short8*)(smB + 32768 + (ht * 16 + lrow) * 512 +
                        ((ks * 64 + lgrp * 16) ^ (lrow << 4)));
                    o[ht] = __builtin_amdgcn_mfma_f32_16x16x32_bf16(pa, vfr, o[ht], 0, 0, 0);
                }
            }
        }

        float* outp = out + ((size_t)b * Tt + i0) * Hh;
#pragma unroll
        for (int r = 0; r < 4; ++r)
#pragma unroll
            for (int ht = 0; ht < 4; ++ht)
                outp[(lgrp * 4 + r) * Hh + ht * 16 + lrow] = o[ht][r] * inv[r];
    }
}

// ---------------------------------------------------------------------------
extern "C" void kernel_launch(void* const* d_in, const int* in_sizes, int n_in,
                              void* d_out, int out_size, void* d_ws, size_t ws_size,
                              hipStream_t stream) {
    const float* x  = (const float*)d_in[0];
    const float* Wq = (const float*)d_in[1];
    const float* Wk = (const float*)d_in[2];
    const float* Wv = (const float*)d_in[3];
    const int* pad  = (const int*)d_in[4];
    float* out = (float*)d_out;

    u16* Wf = (u16*)d_ws;    // 294912 B

    wt_kernel<<<576, 256, 0, stream>>>(Wq, Wk, Wv, Wf);
    fused_kernel<<<Bb, 512, 0, stream>>>(x, Wf, pad, out);
}

// Round 12
// 121.924 us; speedup vs baseline: 1.4073x; 1.4073x over previous
//
#include <hip/hip_runtime.h>
#include <hip/hip_bf16.h>

typedef unsigned short u16;
typedef unsigned int u32;
typedef __attribute__((ext_vector_type(8))) short short8;   // 8 bf16 (4 VGPRs)
typedef __attribute__((ext_vector_type(4))) float f32x4;    // MFMA accumulator
typedef __attribute__((ext_vector_type(4))) u16 u16x4;

static constexpr int Bb = 512, Tt = 256, Cc = 768, Hh = 64;

__device__ __forceinline__ u16 f2bf(float f) {
    __hip_bfloat16 h = __float2bfloat16(f);   // RNE
    union { __hip_bfloat16 h; u16 u; } v; v.h = h;
    return v.u;
}

__device__ __forceinline__ void gll16(const u16* g, u16* l) {
    __builtin_amdgcn_global_load_lds(
        (const __attribute__((address_space(1))) u32*)g,
        (__attribute__((address_space(3))) u32*)l, 16, 0, 0);
}

// ---------------------------------------------------------------------------
// Kernel 0: Wq|Wk|Wv -> k-PAIR-chunked fragment-major bf16 image (24576 B per
// pair j, covering k in [j*64, j*64+64)): sub s = (k>>5)&1, frag nt = n>>4,
// lane lf = (n&15) + ((k>>3)&3)*16, elem e = k&7.
// Staged linearly with global_load_lds; read as 1 KB frags at l*16.
// ---------------------------------------------------------------------------
__global__ void wt_kernel(const float* __restrict__ Wq, const float* __restrict__ Wk,
                          const float* __restrict__ Wv, u16* __restrict__ Wf) {
    int idx = blockIdx.x * 256 + threadIdx.x;          // 192*768
    int n = idx / Cc, k = idx % Cc;
    const float* W = (n < 64) ? Wq : (n < 128) ? Wk : Wv;
    float val = W[k * Hh + (n & 63)];
    int nt = n >> 4, fr = n & 15;
    int j = k >> 6, s = (k >> 5) & 1;
    int lf = fr + (((k >> 3) & 3) << 4), e = k & 7;
    Wf[(size_t)j * 12288 + s * 6144 + nt * 512 + lf * 8 + e] = f2bf(val);
}

// ---------------------------------------------------------------------------
// Fused kernel: one block per batch, 512 thr = 8 waves.
// Phase 1 (QKV GEMM, K_STEP=32, 24 chunks): ALL staging via global_load_lds,
//   counted vmcnt (no "memory" clobbers -> no backend drain), raw s_barrier,
//   x staged as RAW F32 (triple-buffered 3x32KB, swizzled via pre-swizzled
//   global source), W pair-double-buffered (2x24KB). Chunk c:
//     vmcnt(4 even | 7 odd); s_barrier; sched_barrier;
//     STAGE_X(c+2) [4 gll16] (+STAGE_W(c/2+1) [3 gll16] on even c);
//     COMPUTE(c) [reads f32 x -> cvt -> 2 A-frags; 12 W frags; 24 MFMA].
//   NO vmem drain in the loop; x loads ride ~2 chunks across barriers.
//   Race-check: STAGE_X(c+2) targets buf (c+2)%3=(c-1)%3, last read by
//   COMPUTE(c-1); all waves passed barrier(c) => COMPUTE(c-1) done. Safe.
// Epilogue: acc -> KT [256][64], VT [64][256], QB [256][64] -> Q frags.
// Phase 2 (causal attention, per-wave) — unchanged from r7 (passing).
// LDS (147456 B): p1: XS3 [0,98304) | WS2 [98304,147456)
//                 p2: KT [0,32768) | VT [32768,65536) | QB/P [65536,98304)
// ---------------------------------------------------------------------------
__global__ __launch_bounds__(512, 2) void fused_kernel(
        const float* __restrict__ x, const u16* __restrict__ Wf,
        const int* __restrict__ pad, float* __restrict__ out) {
    __shared__ u16 smem[73728];   // 147456 B
    char* smB = (char*)smem;

    const int tid = threadIdx.x;
    const int w = tid >> 6, l = tid & 63;
    const int lrow = l & 15, lgrp = l >> 4;
    const int b = blockIdx.x;
    const int cswz = (lrow & 7) << 4;
    const int tt0 = w, tt1 = 15 - w;          // owned query-row tiles (balanced)

    f32x4 acc[2][12];
#pragma unroll
    for (int i = 0; i < 2; ++i)
#pragma unroll
        for (int j = 0; j < 12; ++j) acc[i][j] = (f32x4)0.f;

// Stage x chunk c_ (k in [c_*32, c_*32+32)) as raw f32 into XS buf tb_.
// LDS image: [row][128B] ^ row-swizzle, achieved by pre-swizzling the GLOBAL
// source (linear LDS dest, rule #21).  Coalescing: per p, 8 rows x 128 B.
#define STAGE_X(c_, tb_)                                                       \
    _Pragma("unroll")                                                          \
    for (int p = 0; p < 4; ++p) {                                              \
        int off = p * 8192 + tid * 16;                                         \
        int row = off >> 7;                                                    \
        int kb = (off & 127) ^ ((row & 7) << 4);                               \
        gll16((const u16*)(x + ((size_t)b * Tt + row) * Cc + (c_) * 32 + (kb >> 2)), \
              smem + (tb_) * 16384 + p * 4096 + w * 512);                      \
    }

// Stage W pair j_ (24576 B) into WS buf wb_.
#define STAGE_W(j_, wb_)                                                       \
    _Pragma("unroll")                                                          \
    for (int q = 0; q < 3; ++q)                                                \
        gll16(Wf + (size_t)(j_) * 12288 + q * 4096 + w * 512 + l * 8,          \
              smem + 49152 + (wb_) * 12288 + q * 4096 + w * 512);

#define COMPUTE(xb_, wb_, ws_)                                                 \
    {                                                                          \
        const char* wp = smB + 98304 + (wb_) * 24576 + (ws_) * 12288;          \
        short8 bfr[12];                                                        \
        _Pragma("unroll")                                                      \
        for (int nt = 0; nt < 12; ++nt)                                        \
            bfr[nt] = *(const short8*)(wp + nt * 1024 + l * 16);               \
        short8 af[2];                                                          \
        _Pragma("unroll")                                                      \
        for (int mt = 0; mt < 2; ++mt) {                                       \
            int row = ((mt == 0) ? tt0 : tt1) * 16 + lrow;                     \
            const char* xp = smB + (xb_) * 32768 + row * 128;                  \
            float4 a0 = *(const float4*)(xp + ((lgrp * 32) ^ ((row & 7) << 4))); \
            float4 a1 = *(const float4*)(xp + ((lgrp * 32 + 16) ^ ((row & 7) << 4))); \
            short8 t;                                                          \
            t[0] = (short)f2bf(a0.x); t[1] = (short)f2bf(a0.y);                \
            t[2] = (short)f2bf(a0.z); t[3] = (short)f2bf(a0.w);                \
            t[4] = (short)f2bf(a1.x); t[5] = (short)f2bf(a1.y);                \
            t[6] = (short)f2bf(a1.z); t[7] = (short)f2bf(a1.w);                \
            af[mt] = t;                                                        \
        }                                                                      \
        _Pragma("unroll")                                                      \
        for (int mt = 0; mt < 2; ++mt)                                         \
            _Pragma("unroll")                                                  \
            for (int nt = 0; nt < 12; ++nt)                                    \
                acc[mt][nt] = __builtin_amdgcn_mfma_f32_16x16x32_bf16(         \
                    af[mt], bfr[nt], acc[mt][nt], 0, 0, 0);                    \
    }

// Chunk c_: literal vmcnt VM_, optional stage flags.  sched_barrier(0) pins
// keep stages below the barrier and ds_reads inside the chunk (rule #18).
#define CHUNK(c_, VM_, SX_, SW_)                                               \
    asm volatile("s_waitcnt vmcnt(" #VM_ ")");                                 \
    __builtin_amdgcn_s_barrier();                                              \
    __builtin_amdgcn_sched_barrier(0);                                         \
    if (SX_) { STAGE_X((c_) + 2, ((c_) + 2) % 3) }                             \
    if (SW_) { STAGE_W((c_) / 2 + 1, ((c_) / 2 + 1) & 1) }                     \
    COMPUTE((c_) % 3, ((c_) >> 1) & 1, (c_) & 1);                              \
    __builtin_amdgcn_sched_barrier(0);

    // ---- Phase 1 prologue: issue x0, W0, x1 (order fixes the vmcnt ledger)
    STAGE_X(0, 0)
    STAGE_W(0, 0)
    STAGE_X(1, 1)

    CHUNK(0, 4, 1, 1)   CHUNK(1, 7, 1, 0)
    CHUNK(2, 4, 1, 1)   CHUNK(3, 7, 1, 0)
    CHUNK(4, 4, 1, 1)   CHUNK(5, 7, 1, 0)
    CHUNK(6, 4, 1, 1)   CHUNK(7, 7, 1, 0)
    CHUNK(8, 4, 1, 1)   CHUNK(9, 7, 1, 0)
    CHUNK(10, 4, 1, 1)  CHUNK(11, 7, 1, 0)
    CHUNK(12, 4, 1, 1)  CHUNK(13, 7, 1, 0)
    CHUNK(14, 4, 1, 1)  CHUNK(15, 7, 1, 0)
    CHUNK(16, 4, 1, 1)  CHUNK(17, 7, 1, 0)
    CHUNK(18, 4, 1, 1)  CHUNK(19, 7, 1, 0)
    CHUNK(20, 4, 1, 1)  CHUNK(21, 7, 1, 0)
    CHUNK(22, 4, 0, 0)  CHUNK(23, 0, 0, 0)

    __syncthreads();            // all chunk-23 reads done before LDS re-purpose
#undef STAGE_X
#undef STAGE_W
#undef COMPUTE
#undef CHUNK

    // ---- Epilogue: acc -> KT / VT / QB ----
#pragma unroll
    for (int mrep = 0; mrep < 2; ++mrep) {
        const int tt = (mrep == 0) ? tt0 : tt1;
        const int s0 = tt * 16;
#pragma unroll
        for (int nt = 0; nt < 12; ++nt) {
            f32x4 a = acc[mrep][nt];
            if (nt < 4) {                       // Q -> QB [256][64]
                int h = nt * 16 + lrow;
#pragma unroll
                for (int r = 0; r < 4; ++r) {
                    int row = s0 + lgrp * 4 + r;
                    *(u16*)(smB + 65536 + ((row * 128 + h * 2) ^ ((row & 7) << 4))) = f2bf(a[r]);
                }
            } else if (nt < 8) {                // K -> KT [256][64]
                int h = (nt - 4) * 16 + lrow;
#pragma unroll
                for (int r = 0; r < 4; ++r) {
                    int s = s0 + lgrp * 4 + r;
                    *(u16*)(smB + ((s * 128 + h * 2) ^ ((s & 7) << 4))) = f2bf(a[r]);
                }
            } else {                            // V -> VT [64][256]
                int h = (nt - 8) * 16 + lrow;
                int s = s0 + lgrp * 4;
                u16x4 pk;
                pk[0] = f2bf(a[0]); pk[1] = f2bf(a[1]);
                pk[2] = f2bf(a[2]); pk[3] = f2bf(a[3]);
                *(u16x4*)(smB + 32768 + h * 512 + ((s * 2) ^ ((h & 15) << 4))) = pk;
            }
        }
    }
    __syncthreads();

    // Q fragment readback
    short8 qfr[2][2];
#pragma unroll
    for (int mt = 0; mt < 2; ++mt) {
        const int tt = (mt == 0) ? tt0 : tt1;
#pragma unroll
        for (int kk = 0; kk < 2; ++kk)
            qfr[mt][kk] = *(const short8*)(smB + 65536 +
                (((tt * 16 + lrow) * 128 + kk * 64 + lgrp * 16) ^ cswz));
    }
    __syncthreads();    // all qfr reads done before P overwrites QB space

    // ---- Phase 2: causal attention (per-wave, no barriers) ----
    char* pbase = smB + 65536 + w * 2560;      // P aliases QB region
#pragma unroll
    for (int mt = 0; mt < 2; ++mt) {
        const int tt = (mt == 0) ? tt0 : tt1;
        const int i0 = tt * 16;

        f32x4 sreg[16];
#pragma unroll
        for (int t = 0; t < 16; ++t) {
            if (t <= tt) {
                short8 k0 = *(const short8*)(smB +
                    (((t * 16 + lrow) * 128 + lgrp * 16) ^ cswz));
                short8 k1 = *(const short8*)(smB +
                    (((t * 16 + lrow) * 128 + 64 + lgrp * 16) ^ cswz));
                f32x4 s = (f32x4)0.f;
                s = __builtin_amdgcn_mfma_f32_16x16x32_bf16(qfr[mt][0], k0, s, 0, 0, 0);
                s = __builtin_amdgcn_mfma_f32_16x16x32_bf16(qfr[mt][1], k1, s, 0, 0, 0);
                if (t == tt) {
#pragma unroll
                    for (int r = 0; r < 4; ++r) {
                        int i = i0 + lgrp * 4 + r;
                        int sidx = t * 16 + lrow;
                        sreg[t][r] = (sidx <= i) ? s[r] * 0.125f : -1e30f;
                    }
                } else {
#pragma unroll
                    for (int r = 0; r < 4; ++r) sreg[t][r] = s[r] * 0.125f;
                }
            }
        }

        f32x4 mx = (f32x4)(-1e30f);
#pragma unroll
        for (int t = 0; t < 16; ++t)
            if (t <= tt)
#pragma unroll
                for (int r = 0; r < 4; ++r) mx[r] = fmaxf(mx[r], sreg[t][r]);
#pragma unroll
        for (int m = 1; m <= 8; m <<= 1)
#pragma unroll
            for (int r = 0; r < 4; ++r) mx[r] = fmaxf(mx[r], __shfl_xor(mx[r], m, 64));

        f32x4 sm = (f32x4)0.f;
#pragma unroll
        for (int t = 0; t < 16; ++t)
            if (t <= tt)
#pragma unroll
                for (int r = 0; r < 4; ++r) {
                    float p = __expf(sreg[t][r] - mx[r]);
                    sreg[t][r] = p;
                    sm[r] += p;
                }
#pragma unroll
        for (int m = 1; m <= 8; m <<= 1)
#pragma unroll
            for (int r = 0; r < 4; ++r) sm[r] += __shfl_xor(sm[r], m, 64);

        float inv[4];
#pragma unroll
        for (int r = 0; r < 4; ++r) {
            int i = i0 + lgrp * 4 + r;
            inv[r] = (pad[b * Tt + i] != 0) ? (1.0f / sm[r]) : 0.0f;
        }

        f32x4 o[4];
#pragma unroll
        for (int ht = 0; ht < 4; ++ht) o[ht] = (f32x4)0.f;
#pragma unroll
        for (int ks = 0; ks < 8; ++ks) {
            if (2 * ks <= tt) {
                char* pb = pbase + (ks & 1) * 1280;
#pragma unroll
                for (int r = 0; r < 4; ++r) {
                    int prow = lgrp * 4 + r;
                    *(u16*)(pb + prow * 80 + lrow * 2) = f2bf(sreg[2 * ks][r]);
                    u16 pv2 = (2 * ks + 1 <= tt) ? f2bf(sreg[2 * ks + 1][r]) : (u16)0;
                    *(u16*)(pb + prow * 80 + 32 + lrow * 2) = pv2;
                }
                short8 pa = *(const short8*)(pb + lrow * 80 + lgrp * 16);
#pragma unroll
                for (int ht = 0; ht < 4; ++ht) {
                    short8 vfr = *(const short8*)(smB + 32768 + (ht * 16 + lrow) * 512 +
                        ((ks * 64 + lgrp * 16) ^ (lrow << 4)));
                    o[ht] = __builtin_amdgcn_mfma_f32_16x16x32_bf16(pa, vfr, o[ht], 0, 0, 0);
                }
            }
        }

        float* outp = out + ((size_t)b * Tt + i0) * Hh;
#pragma unroll
        for (int r = 0; r < 4; ++r)
#pragma unroll
            for (int ht = 0; ht < 4; ++ht)
                outp[(lgrp * 4 + r) * Hh + ht * 16 + lrow] = o[ht][r] * inv[r];
    }
}

// ---------------------------------------------------------------------------
extern "C" void kernel_launch(void* const* d_in, const int* in_sizes, int n_in,
                              void* d_out, int out_size, void* d_ws, size_t ws_size,
                              hipStream_t stream) {
    const float* x  = (const float*)d_in[0];
    const float* Wq = (const float*)d_in[1];
    const float* Wk = (const float*)d_in[2];
    const float* Wv = (const float*)d_in[3];
    const int* pad  = (const int*)d_in[4];
    float* out = (float*)d_out;

    u16* Wf = (u16*)d_ws;    // 294912 B

    wt_kernel<<<576, 256, 0, stream>>>(Wq, Wk, Wv, Wf);
    fused_kernel<<<Bb, 512, 0, stream>>>(x, Wf, pad, out);
}

// Round 13
// 119.732 us; speedup vs baseline: 1.4331x; 1.0183x over previous
//
#include <hip/hip_runtime.h>
#include <hip/hip_bf16.h>

typedef unsigned short u16;
typedef unsigned int u32;
typedef __attribute__((ext_vector_type(8))) short short8;   // 8 bf16 (4 VGPRs)
typedef __attribute__((ext_vector_type(4))) float f32x4;    // MFMA accumulator
typedef __attribute__((ext_vector_type(4))) u16 u16x4;

static constexpr int Bb = 512, Tt = 256, Cc = 768, Hh = 64;

__device__ __forceinline__ u16 f2bf(float f) {
    __hip_bfloat16 h = __float2bfloat16(f);   // RNE
    union { __hip_bfloat16 h; u16 u; } v; v.h = h;
    return v.u;
}

__device__ __forceinline__ void gll16(const u16* g, u16* l) {
    __builtin_amdgcn_global_load_lds(
        (const __attribute__((address_space(1))) u32*)g,
        (__attribute__((address_space(3))) u32*)l, 16, 0, 0);
}

// ---------------------------------------------------------------------------
// Kernel 0: Wq|Wk|Wv -> per-K-chunk fragment-major image:
//   chunk kc holds 24 frags of 1 KB: f = ksub*12 + nt; lane l of frag f gives
//   n = nt*16+(l&15), k = kc*64+ksub*32+(l>>4)*8+e.
// ---------------------------------------------------------------------------
__global__ void wt_kernel(const float* __restrict__ Wq, const float* __restrict__ Wk,
                          const float* __restrict__ Wv, u16* __restrict__ Wf) {
    int idx = blockIdx.x * 256 + threadIdx.x;          // 192*768
    int n = idx / Cc, k = idx % Cc;
    const float* W = (n < 64) ? Wq : (n < 128) ? Wk : Wv;
    float val = W[k * Hh + (n & 63)];
    int nt = n >> 4, fr = n & 15;
    int kc = k >> 6, ksub = (k >> 5) & 1, fk = k & 31;
    Wf[kc * 12288 + (ksub * 12 + nt) * 512 + (fr + ((fk >> 3) << 4)) * 8 + (fk & 7)] = f2bf(val);
}

// ---------------------------------------------------------------------------
// Fused kernel: one block per batch. 512 thr = 8 waves.
// IDENTICAL to the round-7 champion (120.2 us) except ONE change: per-block
// K-CHUNK ROTATION — block b processes chunks ((b%12)+j)%12, j=0..11, so
// concurrent blocks read 12 different k-phases of the stride-3072B pattern
// simultaneously (decorrelates HBM channel load across CUs).  Accumulation
// order change is numerically benign (bf16 products, f32 acc).
// LDS map (bytes): phase1: XS dbuf [0,65536) | WS dbuf [65536,114688)
//                  phase2: KT [0,32768) | VT [32768,65536) | QB/P [65536,98304)
//                  P at [98304,118784)
// ---------------------------------------------------------------------------
__global__ __launch_bounds__(512, 2) void fused_kernel(
        const float* __restrict__ x, const u16* __restrict__ Wf,
        const int* __restrict__ pad, float* __restrict__ out) {
    __shared__ u16 smem[59392];   // 118784 B
    char* smB = (char*)smem;

    const int tid = threadIdx.x;
    const int w = tid >> 6, l = tid & 63;
    const int lrow = l & 15, lgrp = l >> 4;
    const int b = blockIdx.x;
    const int cswz = (lrow & 7) << 4;
    const int tt0 = w, tt1 = 15 - w;          // owned query-row tiles
    const int c0 = b % 12;                     // per-block chunk rotation phase

    const float* xg = x + ((size_t)b * Tt + (tid >> 4)) * Cc + (tid & 15) * 4;

    float4 xr[8];
    f32x4 acc[2][12];
#pragma unroll
    for (int i = 0; i < 2; ++i)
#pragma unroll
        for (int j = 0; j < 12; ++j) acc[i][j] = (f32x4)0.f;

#define XLOAD(kc_)                                                             \
    _Pragma("unroll")                                                          \
    for (int j = 0; j < 8; ++j)                                                \
        xr[j] = *(const float4*)(xg + (size_t)j * 32 * Cc + (kc_) * 64);

#define XWRITE(nb_)                                                            \
    {                                                                          \
        char* xb_ = smB + (nb_) * 32768;                                       \
        _Pragma("unroll")                                                      \
        for (int j = 0; j < 8; ++j) {                                          \
            int row = j * 32 + (tid >> 4);                                     \
            u16x4 pk;                                                          \
            pk[0] = f2bf(xr[j].x); pk[1] = f2bf(xr[j].y);                      \
            pk[2] = f2bf(xr[j].z); pk[3] = f2bf(xr[j].w);                      \
            *(u16x4*)(xb_ + ((row * 128 + (tid & 15) * 8) ^ ((row & 7) << 4))) = pk; \
        }                                                                      \
    }

#define WSTAGE(kc_, nb_)                                                       \
    {                                                                          \
        u16* wl_ = smem + 32768 + (nb_) * 12288;                               \
        const u16* wg_ = Wf + (size_t)(kc_) * 12288;                           \
        _Pragma("unroll")                                                      \
        for (int p = 0; p < 3; ++p)                                            \
            gll16(wg_ + (p * 8 + w) * 512 + l * 8, wl_ + (p * 8 + w) * 512);   \
    }

#define COMPUTE(cur_)                                                          \
    {                                                                          \
        const char* xb = smB + (cur_) * 32768;                                 \
        const char* wb = smB + 65536 + (cur_) * 24576;                         \
        _Pragma("unroll")                                                      \
        for (int ksub = 0; ksub < 2; ++ksub) {                                 \
            short8 bfr[12], af[2];                                             \
            _Pragma("unroll")                                                  \
            for (int nt = 0; nt < 12; ++nt)                                    \
                bfr[nt] = *(const short8*)(wb + (ksub * 12 + nt) * 1024 + l * 16); \
            af[0] = *(const short8*)(xb +                                      \
                (((tt0 * 16 + lrow) * 128 + ksub * 64 + lgrp * 16) ^ cswz));   \
            af[1] = *(const short8*)(xb +                                      \
                (((tt1 * 16 + lrow) * 128 + ksub * 64 + lgrp * 16) ^ cswz));   \
            _Pragma("unroll")                                                  \
            for (int mrep = 0; mrep < 2; ++mrep)                               \
                _Pragma("unroll")                                              \
                for (int nt = 0; nt < 12; ++nt)                                \
                    acc[mrep][nt] = __builtin_amdgcn_mfma_f32_16x16x32_bf16(   \
                        af[mrep], bfr[nt], acc[mrep][nt], 0, 0, 0);            \
        }                                                                      \
    }

    // ---- Phase 1 (rotated chunk order) ----
    XLOAD(c0); WSTAGE(c0, 0); XWRITE(0);
    __syncthreads();
    int pn = c0;                               // pn tracks (c0+kc+1)%12
    for (int kc = 0; kc < 12; ++kc) {
        const int cur = kc & 1;
        pn = (pn == 11) ? 0 : pn + 1;
        if (kc < 11) { WSTAGE(pn, cur ^ 1); XLOAD(pn); }
        COMPUTE(cur);
        if (kc < 11) { XWRITE(cur ^ 1); }
        __syncthreads();
    }
#undef XLOAD
#undef XWRITE
#undef WSTAGE
#undef COMPUTE

    // ---- Epilogue: acc -> KT / VT / QB ----
#pragma unroll
    for (int mrep = 0; mrep < 2; ++mrep) {
        const int tt = (mrep == 0) ? tt0 : tt1;
        const int s0 = tt * 16;
#pragma unroll
        for (int nt = 0; nt < 12; ++nt) {
            f32x4 a = acc[mrep][nt];
            if (nt < 4) {                       // Q -> QB [256][64]
                int h = nt * 16 + lrow;
#pragma unroll
                for (int r = 0; r < 4; ++r) {
                    int row = s0 + lgrp * 4 + r;
                    *(u16*)(smB + 65536 + ((row * 128 + h * 2) ^ ((row & 7) << 4))) = f2bf(a[r]);
                }
            } else if (nt < 8) {                // K -> KT [256][64]
                int h = (nt - 4) * 16 + lrow;
#pragma unroll
                for (int r = 0; r < 4; ++r) {
                    int s = s0 + lgrp * 4 + r;
                    *(u16*)(smB + ((s * 128 + h * 2) ^ ((s & 7) << 4))) = f2bf(a[r]);
                }
            } else {                            // V -> VT [64][256]
                int h = (nt - 8) * 16 + lrow;
                int s = s0 + lgrp * 4;
                u16x4 pk;
                pk[0] = f2bf(a[0]); pk[1] = f2bf(a[1]);
                pk[2] = f2bf(a[2]); pk[3] = f2bf(a[3]);
                *(u16x4*)(smB + 32768 + h * 512 + ((s * 2) ^ ((h & 15) << 4))) = pk;
            }
        }
    }
    __syncthreads();

    // Q fragment readback
    short8 qfr[2][2];
#pragma unroll
    for (int mt = 0; mt < 2; ++mt) {
        const int tt = (mt == 0) ? tt0 : tt1;
#pragma unroll
        for (int kk = 0; kk < 2; ++kk)
            qfr[mt][kk] = *(const short8*)(smB + 65536 +
                (((tt * 16 + lrow) * 128 + kk * 64 + lgrp * 16) ^ cswz));
    }
    __syncthreads();    // all qfr reads done before P overwrites QB space

    // ---- Phase 2: causal attention (per-wave, no barriers) ----
    char* pbase = smB + 98304 + w * 2560;
#pragma unroll
    for (int mt = 0; mt < 2; ++mt) {
        const int tt = (mt == 0) ? tt0 : tt1;
        const int i0 = tt * 16;

        f32x4 sreg[16];
#pragma unroll
        for (int t = 0; t < 16; ++t) {
            if (t <= tt) {
                short8 k0 = *(const short8*)(smB +
                    (((t * 16 + lrow) * 128 + lgrp * 16) ^ cswz));
                short8 k1 = *(const short8*)(smB +
                    (((t * 16 + lrow) * 128 + 64 + lgrp * 16) ^ cswz));
                f32x4 s = (f32x4)0.f;
                s = __builtin_amdgcn_mfma_f32_16x16x32_bf16(qfr[mt][0], k0, s, 0, 0, 0);
                s = __builtin_amdgcn_mfma_f32_16x16x32_bf16(qfr[mt][1], k1, s, 0, 0, 0);
                if (t == tt) {
#pragma unroll
                    for (int r = 0; r < 4; ++r) {
                        int i = i0 + lgrp * 4 + r;
                        int sidx = t * 16 + lrow;
                        sreg[t][r] = (sidx <= i) ? s[r] * 0.125f : -1e30f;
                    }
                } else {
#pragma unroll
                    for (int r = 0; r < 4; ++r) sreg[t][r] = s[r] * 0.125f;
                }
            }
        }

        f32x4 mx = (f32x4)(-1e30f);
#pragma unroll
        for (int t = 0; t < 16; ++t)
            if (t <= tt)
#pragma unroll
                for (int r = 0; r < 4; ++r) mx[r] = fmaxf(mx[r], sreg[t][r]);
#pragma unroll
        for (int m = 1; m <= 8; m <<= 1)
#pragma unroll
            for (int r = 0; r < 4; ++r) mx[r] = fmaxf(mx[r], __shfl_xor(mx[r], m, 64));

        f32x4 sm = (f32x4)0.f;
#pragma unroll
        for (int t = 0; t < 16; ++t)
            if (t <= tt)
#pragma unroll
                for (int r = 0; r < 4; ++r) {
                    float p = __expf(sreg[t][r] - mx[r]);
                    sreg[t][r] = p;
                    sm[r] += p;
                }
#pragma unroll
        for (int m = 1; m <= 8; m <<= 1)
#pragma unroll
            for (int r = 0; r < 4; ++r) sm[r] += __shfl_xor(sm[r], m, 64);

        float inv[4];
#pragma unroll
        for (int r = 0; r < 4; ++r) {
            int i = i0 + lgrp * 4 + r;
            inv[r] = (pad[b * Tt + i] != 0) ? (1.0f / sm[r]) : 0.0f;
        }

        f32x4 o[4];
#pragma unroll
        for (int ht = 0; ht < 4; ++ht) o[ht] = (f32x4)0.f;
#pragma unroll
        for (int ks = 0; ks < 8; ++ks) {
            if (2 * ks <= tt) {
                char* pb = pbase + (ks & 1) * 1280;
#pragma unroll
                for (int r = 0; r < 4; ++r) {
                    int prow = lgrp * 4 + r;
                    *(u16*)(pb + prow * 80 + lrow * 2) = f2bf(sreg[2 * ks][r]);
                    u16 pv2 = (2 * ks + 1 <= tt) ? f2bf(sreg[2 * ks + 1][r]) : (u16)0;
                    *(u16*)(pb + prow * 80 + 32 + lrow * 2) = pv2;
                }
                short8 pa = *(const short8*)(pb + lrow * 80 + lgrp * 16);
#pragma unroll
                for (int ht = 0; ht < 4; ++ht) {
                    short8 vfr = *(const short8*)(smB + 32768 + (ht * 16 + lrow) * 512 +
                        ((ks * 64 + lgrp * 16) ^ (lrow << 4)));
                    o[ht] = __builtin_amdgcn_mfma_f32_16x16x32_bf16(pa, vfr, o[ht], 0, 0, 0);
                }
            }
        }

        float* outp = out + ((size_t)b * Tt + i0) * Hh;
#pragma unroll
        for (int r = 0; r < 4; ++r)
#pragma unroll
            for (int ht = 0; ht < 4; ++ht)
                outp[(lgrp * 4 + r) * Hh + ht * 16 + lrow] = o[ht][r] * inv[r];
    }
}

// ---------------------------------------------------------------------------
extern "C" void kernel_launch(void* const* d_in, const int* in_sizes, int n_in,
                              void* d_out, int out_size, void* d_ws, size_t ws_size,
                              hipStream_t stream) {
    const float* x  = (const float*)d_in[0];
    const float* Wq = (const float*)d_in[1];
    const float* Wk = (const float*)d_in[2];
    const float* Wv = (const float*)d_in[3];
    const int* pad  = (const int*)d_in[4];
    float* out = (float*)d_out;

    u16* Wf = (u16*)d_ws;    // 294912 B

    wt_kernel<<<576, 256, 0, stream>>>(Wq, Wk, Wv, Wf);
    fused_kernel<<<Bb, 512, 0, stream>>>(x, Wf, pad, out);
}